// Round 7
// baseline (441.591 us; speedup 1.0000x reference)
//
#include <hip/hip_runtime.h>
#include <hip/hip_bf16.h>

// LSTMFeatureExtractor: 2-layer LSTM (H=64, IN=1, B=2048, T=512) + FC(64->32)+ReLU
// R7: MB=8, grid 256, 512 threads (8 SYMMETRIC waves, 2/SIMD). Halves MFMA
// row-redundancy vs MB=4: 24 MFMA/SIMD/iter = 432 cy floor (measured m06 rate
// is ~19 cy/MFMA *per SIMD*; R6 showed we sit at that throughput ceiling).
// Each wave: 8 units x 4 gates x both layers = 12 MFMA, gate-interleaved cols
// (tileA={i,f}, tileB={g,o}); duplicate row-quads split by LAYER (quads 0-1:
// L0 cells, 2-3: L1 cells) so one instruction stream serves both layers;
// even/odd lanes split {i,g}/{f,o} acts, 4x shfl_xor(1) to exchange.
// Bias + x*Wih0 seeded into MFMA C operand.

#define HID 64
#define TSTEPS 512
#define MB 8
#define RS 80   // f16 row stride: 160B = 8 words mod 32 -> <=2-way (free)

typedef _Float16 f16x8 __attribute__((ext_vector_type(8)));
typedef float f32x4 __attribute__((ext_vector_type(4)));

#define KSIG (-1.44269504089f)   // -log2(e)
#define KTANH (2.88539008178f)   // 2*log2(e)

__global__ __launch_bounds__(512, 2) void lstm_feat_kernel(
    const float* __restrict__ x,
    const float* __restrict__ Wih0, const float* __restrict__ Whh0,
    const float* __restrict__ bih0, const float* __restrict__ bhh0,
    const float* __restrict__ Wih1, const float* __restrict__ Whh1,
    const float* __restrict__ bih1, const float* __restrict__ bhh1,
    const float* __restrict__ fcW, const float* __restrict__ fcb,
    float* __restrict__ out)
{
    __shared__ float x_lds[TSTEPS * MB];                   // [t][row], 16 KB
    __shared__ __align__(16) _Float16 h0_lds[2][MB * RS];
    __shared__ __align__(16) _Float16 h1_lds[2][MB * RS];
    __shared__ float h1f32[MB * HID];
    __shared__ float fcw_lds[32 * HID];
    __shared__ float fcb_lds[32];

    const int tid  = threadIdx.x;
    const int wave = tid >> 6;      // 0..7: owns units [8w, 8w+8)
    const int lane = tid & 63;
    const int nq   = lane & 15;
    const int quad = lane >> 4;
    const bool l0q  = quad < 2;         // quads 0-1: layer-0 cells; 2-3: layer-1
    const bool evn  = (nq & 1) == 0;    // even lanes: {i,g}; odd: {f,o}
    const int ucell = wave * 8 + (nq >> 1);   // unit this lane-pair owns
    const int bbase = blockIdx.x * MB;

    // ---- one-time staging ----
    for (int i = tid; i < TSTEPS * MB; i += 512) {
        int r = i >> 9, t = i & (TSTEPS - 1);
        x_lds[t * MB + r] = x[(bbase + r) * TSTEPS + t];   // coalesced in t
    }
    for (int i = tid; i < 32 * HID; i += 512) fcw_lds[i] = fcW[i];
    if (tid < 32) fcb_lds[tid] = fcb[tid];
    for (int i = tid; i < 2 * MB * RS; i += 512) {
        ((_Float16*)h0_lds)[i] = (_Float16)0.f;            // H0[0]=0 (both bufs)
        ((_Float16*)h1_lds)[i] = (_Float16)0.f;            // H1[0]=0 (both bufs)
    }

    // ---- per-lane weight fragments (B operand), gate-interleaved cols ----
    // tileA col nq -> (unit ucell, gate nq&1 in {i,f}); tileB -> {g,o}
    const int nA = (nq & 1) * 64 + ucell;        // W row for gate i or f
    const int nB = (2 + (nq & 1)) * 64 + ucell;  // W row for gate g or o
    f16x8 wA0[2], wB0[2], wiA[2], whA[2], wiB[2], whB[2];
    #pragma unroll
    for (int ks = 0; ks < 2; ++ks) {
        const int k0 = quad * 8 + ks * 32;
        f16x8 a, b, c, d, e, f;
        #pragma unroll
        for (int j = 0; j < 8; ++j) {
            a[j] = (_Float16)Whh0[nA * HID + k0 + j];
            b[j] = (_Float16)Whh0[nB * HID + k0 + j];
            c[j] = (_Float16)Wih1[nA * HID + k0 + j];
            d[j] = (_Float16)Whh1[nA * HID + k0 + j];
            e[j] = (_Float16)Wih1[nB * HID + k0 + j];
            f[j] = (_Float16)Whh1[nB * HID + k0 + j];
        }
        wA0[ks] = a; wB0[ks] = b; wiA[ks] = c; whA[ks] = d; wiB[ks] = e; whB[ks] = f;
    }
    const float bA0 = bih0[nA] + bhh0[nA];
    const float bB0 = bih0[nB] + bhh0[nB];
    const float bA1 = bih1[nA] + bhh1[nA];
    const float bB1 = bih1[nB] + bhh1[nB];
    const float wxA = Wih0[nA];          // IN==1
    const float wxB = Wih0[nB];

    // tileB activation: even lanes tanh (A*rcp(1+exp2(k*x))+B), odd sigma
    const float kB = evn ? KTANH : KSIG;
    const float AB = evn ? -2.f : 1.f;
    const float BB = evn ? 1.f : 0.f;

    const f32x4 zero4 = {0.f, 0.f, 0.f, 0.f};
    const f32x4 biasA1 = {bA1, bA1, bA1, bA1};
    const f32x4 biasB1 = {bB1, bB1, bB1, bB1};
    const int arow = (nq & 7) * RS + quad * 8;   // A row m = h[batch m&7]
    float cst[2] = {0.f, 0.f};    // c-state for this lane's 2 cells (its layer)
    float hl[2]  = {0.f, 0.f};    // last h written (L1 lanes keep H1[512])

    __syncthreads();

    // ---- skewed recurrence, 513 iters, 1 barrier each:
    //      iter k: L0 makes H0[k+1] (k<512), L1 makes H1[k] (k>=1) ----
    int p = 0;
    for (int k = 0; k <= TSTEPS; ++k) {
        const int q = p ^ 1;

        f16x8 a00 = *(const f16x8*)&h0_lds[p][arow];
        f16x8 a01 = *(const f16x8*)&h0_lds[p][arow + 32];
        f16x8 a10 = *(const f16x8*)&h1_lds[p][arow];
        f16x8 a11 = *(const f16x8*)&h1_lds[p][arow + 32];
        const int kx = (k < TSTEPS) ? k : (TSTEPS - 1);
        const float4 xv = *(const float4*)&x_lds[kx * MB + ((quad * 4) & 7)];
        const float xr[4] = {xv.x, xv.y, xv.z, xv.w};

        // C-seeds: L0 gets bias + x*Wih0 (per-row batch x); L1 gets bias.
        f32x4 cA, cB;
        #pragma unroll
        for (int r = 0; r < 4; ++r) {
            cA[r] = fmaf(xr[r], wxA, bA0);
            cB[r] = fmaf(xr[r], wxB, bB0);
        }

        // 6 independent K0 MFMAs, then 6 K1 second-links.
        f32x4 aA0 = __builtin_amdgcn_mfma_f32_16x16x32_f16(a00, wA0[0], cA, 0, 0, 0);
        f32x4 aB0 = __builtin_amdgcn_mfma_f32_16x16x32_f16(a00, wB0[0], cB, 0, 0, 0);
        f32x4 aiA = __builtin_amdgcn_mfma_f32_16x16x32_f16(a00, wiA[0], biasA1, 0, 0, 0);
        f32x4 aiB = __builtin_amdgcn_mfma_f32_16x16x32_f16(a00, wiB[0], biasB1, 0, 0, 0);
        f32x4 ahA = __builtin_amdgcn_mfma_f32_16x16x32_f16(a10, whA[0], zero4, 0, 0, 0);
        f32x4 ahB = __builtin_amdgcn_mfma_f32_16x16x32_f16(a10, whB[0], zero4, 0, 0, 0);
        aA0 = __builtin_amdgcn_mfma_f32_16x16x32_f16(a01, wA0[1], aA0, 0, 0, 0);
        aB0 = __builtin_amdgcn_mfma_f32_16x16x32_f16(a01, wB0[1], aB0, 0, 0, 0);
        aiA = __builtin_amdgcn_mfma_f32_16x16x32_f16(a01, wiA[1], aiA, 0, 0, 0);
        aiB = __builtin_amdgcn_mfma_f32_16x16x32_f16(a01, wiB[1], aiB, 0, 0, 0);
        ahA = __builtin_amdgcn_mfma_f32_16x16x32_f16(a11, whA[1], ahA, 0, 0, 0);
        ahB = __builtin_amdgcn_mfma_f32_16x16x32_f16(a11, whB[1], ahB, 0, 0, 0);

        const bool active = l0q ? (k < TSTEPS) : (k > 0);
        if (active) {
            // pick this quad's layer pre-acts
            float sA[4], sB[4];
            #pragma unroll
            for (int r = 0; r < 4; ++r) {
                const float pA = l0q ? aA0[r] : (aiA[r] + ahA[r]);
                const float pB = l0q ? aB0[r] : (aiB[r] + ahB[r]);
                sA[r] = __builtin_amdgcn_rcpf(1.f + __builtin_amdgcn_exp2f(KSIG * pA));
                sB[r] = AB * __builtin_amdgcn_rcpf(1.f + __builtin_amdgcn_exp2f(kB * pB)) + BB;
            }
            // pair exchange: even keeps elems 0,1 / odd keeps 2,3
            const float rxA0 = __shfl_xor(evn ? sA[2] : sA[0], 1);
            const float rxA1 = __shfl_xor(evn ? sA[3] : sA[1], 1);
            const float rxB0 = __shfl_xor(evn ? sB[2] : sB[0], 1);
            const float rxB1 = __shfl_xor(evn ? sB[3] : sB[1], 1);
            _Float16* hdst = l0q ? h0_lds[q] : h1_lds[q];
            #pragma unroll
            for (int s = 0; s < 2; ++s) {
                const int e = evn ? s : 2 + s;
                const float rxA = s ? rxA1 : rxA0;
                const float rxB = s ? rxB1 : rxB0;
                const float iv = evn ? sA[e] : rxA;
                const float fv = evn ? rxA : sA[e];
                const float gv = evn ? sB[e] : rxB;
                const float ov = evn ? rxB : sB[e];
                cst[s] = fv * cst[s] + iv * gv;
                const float th = 1.f - 2.f * __builtin_amdgcn_rcpf(
                                     1.f + __builtin_amdgcn_exp2f(KTANH * cst[s]));
                const float h = ov * th;
                hl[s] = h;
                const int b = (quad * 4 + e) & 7;
                hdst[b * RS + ucell] = (_Float16)h;
            }
        }
        p = q;
        __syncthreads();
    }

    // ---- epilogue: features = relu(H1[512] @ fcW^T + fcb) ----
    if (!l0q) {
        #pragma unroll
        for (int s = 0; s < 2; ++s) {
            const int e = evn ? s : 2 + s;
            const int b = (quad * 4 + e) & 7;
            h1f32[b * HID + ucell] = hl[s];
        }
    }
    __syncthreads();

    if (tid < MB * 32) {
        const int o  = tid & 31;
        const int rr = tid >> 5;
        float acc = fcb_lds[o];
        #pragma unroll 8
        for (int kk = 0; kk < HID; ++kk)
            acc += h1f32[rr * HID + kk] * fcw_lds[o * HID + kk];
        out[(bbase + rr) * 32 + o] = fmaxf(acc, 0.f);
    }
}

extern "C" void kernel_launch(void* const* d_in, const int* in_sizes, int n_in,
                              void* d_out, int out_size, void* d_ws, size_t ws_size,
                              hipStream_t stream) {
    const float* x    = (const float*)d_in[0];
    const float* Wih0 = (const float*)d_in[1];
    const float* Whh0 = (const float*)d_in[2];
    const float* bih0 = (const float*)d_in[3];
    const float* bhh0 = (const float*)d_in[4];
    const float* Wih1 = (const float*)d_in[5];
    const float* Whh1 = (const float*)d_in[6];
    const float* bih1 = (const float*)d_in[7];
    const float* bhh1 = (const float*)d_in[8];
    const float* fcW  = (const float*)d_in[9];
    const float* fcb  = (const float*)d_in[10];
    float* out = (float*)d_out;

    lstm_feat_kernel<<<2048 / MB, 512, 0, stream>>>(
        x, Wih0, Whh0, bih0, bhh0, Wih1, Whh1, bih1, bhh1, fcW, fcb, out);
}

// Round 8
// 396.617 us; speedup vs baseline: 1.1134x; 1.1134x over previous
//
#include <hip/hip_runtime.h>
#include <hip/hip_bf16.h>

// LSTMFeatureExtractor: 2-layer LSTM (H=64, IN=1, B=2048, T=512) + FC(64->32)+ReLU
// R8 = R7 dataflow (MB=8, grid 256, 512 thr, 12 MFMA/wave = 432 cy/SIMD floor,
// layer-split quads, even/odd gate split + 4x shfl_xor(1)) with a LEAN loop:
//   - peel k=0 (only iter needing a cell mask) -> k=1..512 body is branchless
//   - unroll x2 with LITERAL buffer parity (static LDS bases, no p^1 churn)
//   - L1 = single 4-deep MFMA chain, bias pre-seeded in a loop-invariant C reg
//     (removes the accA+accB adds); dep-distance-2 covered by 2 waves/SIMD
// R7 verified the MFMA half (423 cy/SIMD measured vs 432 predicted); this
// round attacks the +220 cy VALU fat and ~320 cy dead time.

#define HID 64
#define TSTEPS 512
#define MB 8
#define RS 80   // f16 row stride: words/row=40 -> A-frag reads 2-way (free)

typedef _Float16 f16x8 __attribute__((ext_vector_type(8)));
typedef float f32x4 __attribute__((ext_vector_type(4)));

#define KSIG (-1.44269504089f)   // -log2(e)
#define KTANH (2.88539008178f)   // 2*log2(e)

__global__ __launch_bounds__(512, 2) void lstm_feat_kernel(
    const float* __restrict__ x,
    const float* __restrict__ Wih0, const float* __restrict__ Whh0,
    const float* __restrict__ bih0, const float* __restrict__ bhh0,
    const float* __restrict__ Wih1, const float* __restrict__ Whh1,
    const float* __restrict__ bih1, const float* __restrict__ bhh1,
    const float* __restrict__ fcW, const float* __restrict__ fcb,
    float* __restrict__ out)
{
    __shared__ float x_lds[TSTEPS * MB];                   // [t][row], 16 KB
    __shared__ __align__(16) _Float16 h0_lds[2][MB * RS];
    __shared__ __align__(16) _Float16 h1_lds[2][MB * RS];
    __shared__ float h1f32[MB * HID];
    __shared__ float fcw_lds[32 * HID];
    __shared__ float fcb_lds[32];

    const int tid  = threadIdx.x;
    const int wave = tid >> 6;      // 0..7: owns units [8w, 8w+8)
    const int lane = tid & 63;
    const int nq   = lane & 15;
    const int quad = lane >> 4;
    const bool l0q = quad < 2;          // quads 0-1: layer-0 cells; 2-3: layer-1
    const bool evn = (nq & 1) == 0;     // even lanes: {i,g}; odd: {f,o}
    const int ucell = wave * 8 + (nq >> 1);   // unit this lane-pair owns
    const int bbase = blockIdx.x * MB;

    // ---- one-time staging ----
    for (int i = tid; i < TSTEPS * MB; i += 512) {
        int r = i >> 9, t = i & (TSTEPS - 1);
        x_lds[t * MB + r] = x[(bbase + r) * TSTEPS + t];   // coalesced in t
    }
    for (int i = tid; i < 32 * HID; i += 512) fcw_lds[i] = fcW[i];
    if (tid < 32) fcb_lds[tid] = fcb[tid];
    for (int i = tid; i < 2 * MB * RS; i += 512) {
        ((_Float16*)h0_lds)[i] = (_Float16)0.f;            // H0[0]=0 (both bufs)
        ((_Float16*)h1_lds)[i] = (_Float16)0.f;            // H1[0]=0 (both bufs)
    }

    // ---- per-lane weight fragments (B operand), gate-interleaved cols ----
    const int nA = (nq & 1) * 64 + ucell;        // W row for gate i or f
    const int nB = (2 + (nq & 1)) * 64 + ucell;  // W row for gate g or o
    f16x8 wA0[2], wB0[2], wiA[2], whA[2], wiB[2], whB[2];
    #pragma unroll
    for (int ks = 0; ks < 2; ++ks) {
        const int k0 = quad * 8 + ks * 32;
        f16x8 a, b, c, d, e, f;
        #pragma unroll
        for (int j = 0; j < 8; ++j) {
            a[j] = (_Float16)Whh0[nA * HID + k0 + j];
            b[j] = (_Float16)Whh0[nB * HID + k0 + j];
            c[j] = (_Float16)Wih1[nA * HID + k0 + j];
            d[j] = (_Float16)Whh1[nA * HID + k0 + j];
            e[j] = (_Float16)Wih1[nB * HID + k0 + j];
            f[j] = (_Float16)Whh1[nB * HID + k0 + j];
        }
        wA0[ks] = a; wB0[ks] = b; wiA[ks] = c; whA[ks] = d; wiB[ks] = e; whB[ks] = f;
    }
    const float bA0 = bih0[nA] + bhh0[nA];
    const float bB0 = bih0[nB] + bhh0[nB];
    const float bA1 = bih1[nA] + bhh1[nA];
    const float bB1 = bih1[nB] + bhh1[nB];
    const float wxA = Wih0[nA];          // IN==1
    const float wxB = Wih0[nB];

    // tileB activation: even lanes tanh (A*rcp(1+exp2(k*x))+B), odd sigma
    const float kB = evn ? KTANH : KSIG;
    const float AB = evn ? -2.f : 1.f;
    const float BB = evn ? 1.f : 0.f;

    const f32x4 biasA1 = {bA1, bA1, bA1, bA1};   // loop-invariant L1 C-seeds
    const f32x4 biasB1 = {bB1, bB1, bB1, bB1};
    const int arow = (nq & 7) * RS + quad * 8;   // A row m = h[batch m&7]
    const int xoff = (quad & 1) * 4;             // this quad's 4-batch x group
    float cst[2] = {0.f, 0.f};    // c-state for this lane's 2 cells (its layer)
    float hl[2]  = {0.f, 0.f};    // last h written (L1 lanes keep H1[512])

    __syncthreads();

    // One step: reads bufs [p], writes bufs [p^1]. Called with LITERAL p and
    // literal cell-mask flag so everything folds. xk = clamped time index.
    auto step = [&](int xk, int pp, bool maskK0) {
        const int qq = pp ^ 1;
        const f16x8 a00 = *(const f16x8*)&h0_lds[pp][arow];
        const f16x8 a01 = *(const f16x8*)&h0_lds[pp][arow + 32];
        const f16x8 a10 = *(const f16x8*)&h1_lds[pp][arow];
        const f16x8 a11 = *(const f16x8*)&h1_lds[pp][arow + 32];
        const float4 xv = *(const float4*)&x_lds[xk * MB + xoff];

        f32x4 cA, cB;   // L0 C-seeds: bias + x*Wih0 per batch row
        cA[0] = fmaf(xv.x, wxA, bA0); cA[1] = fmaf(xv.y, wxA, bA0);
        cA[2] = fmaf(xv.z, wxA, bA0); cA[3] = fmaf(xv.w, wxA, bA0);
        cB[0] = fmaf(xv.x, wxB, bB0); cB[1] = fmaf(xv.y, wxB, bB0);
        cB[2] = fmaf(xv.z, wxB, bB0); cB[3] = fmaf(xv.w, wxB, bB0);

        // L0: two 2-chains; L1: two 4-chains (bias-seeded, loop-invariant C)
        f32x4 tA = __builtin_amdgcn_mfma_f32_16x16x32_f16(a00, wA0[0], cA, 0, 0, 0);
        f32x4 tB = __builtin_amdgcn_mfma_f32_16x16x32_f16(a00, wB0[0], cB, 0, 0, 0);
        f32x4 uA = __builtin_amdgcn_mfma_f32_16x16x32_f16(a00, wiA[0], biasA1, 0, 0, 0);
        f32x4 uB = __builtin_amdgcn_mfma_f32_16x16x32_f16(a00, wiB[0], biasB1, 0, 0, 0);
        tA = __builtin_amdgcn_mfma_f32_16x16x32_f16(a01, wA0[1], tA, 0, 0, 0);
        tB = __builtin_amdgcn_mfma_f32_16x16x32_f16(a01, wB0[1], tB, 0, 0, 0);
        uA = __builtin_amdgcn_mfma_f32_16x16x32_f16(a01, wiA[1], uA, 0, 0, 0);
        uB = __builtin_amdgcn_mfma_f32_16x16x32_f16(a01, wiB[1], uB, 0, 0, 0);
        uA = __builtin_amdgcn_mfma_f32_16x16x32_f16(a10, whA[0], uA, 0, 0, 0);
        uB = __builtin_amdgcn_mfma_f32_16x16x32_f16(a10, whB[0], uB, 0, 0, 0);
        uA = __builtin_amdgcn_mfma_f32_16x16x32_f16(a11, whA[1], uA, 0, 0, 0);
        uB = __builtin_amdgcn_mfma_f32_16x16x32_f16(a11, whB[1], uB, 0, 0, 0);

        const bool docell = maskK0 ? l0q : true;   // only k=0 masks L1 quads
        if (docell) {
            float sA[4], sB[4];
            #pragma unroll
            for (int r = 0; r < 4; ++r) {
                const float pA = l0q ? tA[r] : uA[r];
                const float pB = l0q ? tB[r] : uB[r];
                sA[r] = __builtin_amdgcn_rcpf(1.f + __builtin_amdgcn_exp2f(KSIG * pA));
                sB[r] = AB * __builtin_amdgcn_rcpf(1.f + __builtin_amdgcn_exp2f(kB * pB)) + BB;
            }
            const float rxA0 = __shfl_xor(evn ? sA[2] : sA[0], 1);
            const float rxA1 = __shfl_xor(evn ? sA[3] : sA[1], 1);
            const float rxB0 = __shfl_xor(evn ? sB[2] : sB[0], 1);
            const float rxB1 = __shfl_xor(evn ? sB[3] : sB[1], 1);
            _Float16* hdst = l0q ? h0_lds[qq] : h1_lds[qq];
            #pragma unroll
            for (int s = 0; s < 2; ++s) {
                const int e = evn ? s : 2 + s;
                const float rxA = s ? rxA1 : rxA0;
                const float rxB = s ? rxB1 : rxB0;
                const float iv = evn ? sA[e] : rxA;
                const float fv = evn ? rxA : sA[e];
                const float gv = evn ? sB[e] : rxB;
                const float ov = evn ? rxB : sB[e];
                cst[s] = fv * cst[s] + iv * gv;
                const float th = 1.f - 2.f * __builtin_amdgcn_rcpf(
                                     1.f + __builtin_amdgcn_exp2f(KTANH * cst[s]));
                const float h = ov * th;
                hl[s] = h;
                const int b = (quad * 4 + e) & 7;
                hdst[b * RS + ucell] = (_Float16)h;
            }
        }
        __syncthreads();
    };

    // peel k=0 (L1 quads must not touch c-state), then branchless k=1..512
    step(0, 0, true);
    for (int k = 1; k < 511; k += 2) {
        step(k, 1, false);
        step(k + 1, 0, false);
    }
    step(511, 1, false);
    step(511, 0, false);   // k=512 tail: L0 output garbage-but-unread; x clamped

    // ---- epilogue: features = relu(H1[512] @ fcW^T + fcb) ----
    if (!l0q) {
        #pragma unroll
        for (int s = 0; s < 2; ++s) {
            const int e = evn ? s : 2 + s;
            const int b = (quad * 4 + e) & 7;
            h1f32[b * HID + ucell] = hl[s];
        }
    }
    __syncthreads();

    if (tid < MB * 32) {
        const int o  = tid & 31;
        const int rr = tid >> 5;
        float acc = fcb_lds[o];
        #pragma unroll 8
        for (int kk = 0; kk < HID; ++kk)
            acc += h1f32[rr * HID + kk] * fcw_lds[o * HID + kk];
        out[(bbase + rr) * 32 + o] = fmaxf(acc, 0.f);
    }
}

extern "C" void kernel_launch(void* const* d_in, const int* in_sizes, int n_in,
                              void* d_out, int out_size, void* d_ws, size_t ws_size,
                              hipStream_t stream) {
    const float* x    = (const float*)d_in[0];
    const float* Wih0 = (const float*)d_in[1];
    const float* Whh0 = (const float*)d_in[2];
    const float* bih0 = (const float*)d_in[3];
    const float* bhh0 = (const float*)d_in[4];
    const float* Wih1 = (const float*)d_in[5];
    const float* Whh1 = (const float*)d_in[6];
    const float* bih1 = (const float*)d_in[7];
    const float* bhh1 = (const float*)d_in[8];
    const float* fcW  = (const float*)d_in[9];
    const float* fcb  = (const float*)d_in[10];
    float* out = (float*)d_out;

    lstm_feat_kernel<<<2048 / MB, 512, 0, stream>>>(
        x, Wih0, Whh0, bih0, bhh0, Wih1, Whh1, bih1, bhh1, fcW, fcb, out);
}

// Round 9
// 378.107 us; speedup vs baseline: 1.1679x; 1.0490x over previous
//
#include <hip/hip_runtime.h>
#include <hip/hip_bf16.h>

// LSTMFeatureExtractor: 2-layer LSTM (H=64, IN=1, B=2048, T=512) + FC(64->32)+ReLU
// R9 = R8 (MB=8, 512 thr, layer-split quads, even/odd gate split, 1 barrier/step)
// with supporting-VALU cuts. R8 analysis: MFMA at throughput floor (420 cy/SIMD),
// trans count at theoretical min (20 instr/wave), bank conflicts phantom
// (data-volume-forced). Remaining lever: non-trans VALU.
//  (a) activation constants folded into weights/biases/wx (per-lane scale
//      KSIG or KTANH) -> exp2 takes MFMA output directly, -8 v_mul/lane
//  (b) f32x2 packed cell math -> v_pk_fma_f32 pairs
//  (c) loop-invariant write addresses + parity pointers hoisted; x-seeds for
//      step k+1 computed in step k's MFMA shadow (off the post-barrier path)

#define HID 64
#define TSTEPS 512
#define MB 8
#define RS 80   // f16 row stride

typedef _Float16 f16x8 __attribute__((ext_vector_type(8)));
typedef float f32x4 __attribute__((ext_vector_type(4)));
typedef float f32x2 __attribute__((ext_vector_type(2)));

#define KSIG (-1.44269504089f)   // -log2(e):  sigma(x) = rcp(1+exp2(KSIG*x))
#define KTANH (2.88539008178f)   // 2*log2(e): tanh(x) = 1-2*rcp(1+exp2(KTANH*x))

__global__ __launch_bounds__(512, 2) void lstm_feat_kernel(
    const float* __restrict__ x,
    const float* __restrict__ Wih0, const float* __restrict__ Whh0,
    const float* __restrict__ bih0, const float* __restrict__ bhh0,
    const float* __restrict__ Wih1, const float* __restrict__ Whh1,
    const float* __restrict__ bih1, const float* __restrict__ bhh1,
    const float* __restrict__ fcW, const float* __restrict__ fcb,
    float* __restrict__ out)
{
    __shared__ float x_lds[TSTEPS * MB];                   // [t][row], 16 KB
    __shared__ __align__(16) _Float16 h0_lds[2][MB * RS];
    __shared__ __align__(16) _Float16 h1_lds[2][MB * RS];
    __shared__ float h1f32[MB * HID];
    __shared__ float fcw_lds[32 * HID];
    __shared__ float fcb_lds[32];

    const int tid  = threadIdx.x;
    const int wave = tid >> 6;      // 0..7: owns units [8w, 8w+8)
    const int lane = tid & 63;
    const int nq   = lane & 15;
    const int quad = lane >> 4;
    const bool l0q = quad < 2;          // quads 0-1: layer-0 cells; 2-3: layer-1
    const bool evn = (nq & 1) == 0;     // even lanes: {i,g}; odd: {f,o}
    const int ucell = wave * 8 + (nq >> 1);   // unit this lane-pair owns
    const int bbase = blockIdx.x * MB;

    // ---- one-time staging ----
    for (int i = tid; i < TSTEPS * MB; i += 512) {
        int r = i >> 9, t = i & (TSTEPS - 1);
        x_lds[t * MB + r] = x[(bbase + r) * TSTEPS + t];   // coalesced in t
    }
    for (int i = tid; i < 32 * HID; i += 512) fcw_lds[i] = fcW[i];
    if (tid < 32) fcb_lds[tid] = fcb[tid];
    for (int i = tid; i < 2 * MB * RS; i += 512) {
        ((_Float16*)h0_lds)[i] = (_Float16)0.f;            // H0[0]=0 (both bufs)
        ((_Float16*)h1_lds)[i] = (_Float16)0.f;            // H1[0]=0 (both bufs)
    }

    // ---- per-lane weight fragments (B operand), gate-interleaved cols,
    //      PRE-SCALED by this lane's activation constants ----
    const int nA = (nq & 1) * 64 + ucell;        // W row for gate i or f (sigma)
    const int nB = (2 + (nq & 1)) * 64 + ucell;  // W row for gate g or o
    const float kBs = evn ? KTANH : KSIG;        // tileB constant (g: tanh, o: sigma)
    f16x8 wA0[2], wB0[2], wiA[2], whA[2], wiB[2], whB[2];
    #pragma unroll
    for (int ks = 0; ks < 2; ++ks) {
        const int k0 = quad * 8 + ks * 32;
        f16x8 a, b, c, d, e, f;
        #pragma unroll
        for (int j = 0; j < 8; ++j) {
            a[j] = (_Float16)(KSIG * Whh0[nA * HID + k0 + j]);
            b[j] = (_Float16)(kBs  * Whh0[nB * HID + k0 + j]);
            c[j] = (_Float16)(KSIG * Wih1[nA * HID + k0 + j]);
            d[j] = (_Float16)(KSIG * Whh1[nA * HID + k0 + j]);
            e[j] = (_Float16)(kBs  * Wih1[nB * HID + k0 + j]);
            f[j] = (_Float16)(kBs  * Whh1[nB * HID + k0 + j]);
        }
        wA0[ks] = a; wB0[ks] = b; wiA[ks] = c; whA[ks] = d; wiB[ks] = e; whB[ks] = f;
    }
    const float bA0 = KSIG * (bih0[nA] + bhh0[nA]);
    const float bB0 = kBs  * (bih0[nB] + bhh0[nB]);
    const float bA1 = KSIG * (bih1[nA] + bhh1[nA]);
    const float bB1 = kBs  * (bih1[nB] + bhh1[nB]);
    const float wxA = KSIG * Wih0[nA];           // IN==1
    const float wxB = kBs  * Wih0[nB];

    // tileB post-form: even lanes tanh -> -2*rcp+1; odd sigma -> rcp
    const float AB = evn ? -2.f : 1.f;
    const float BB = evn ? 1.f : 0.f;

    const f32x4 biasA1 = {bA1, bA1, bA1, bA1};   // loop-invariant L1 C-seeds
    const f32x4 biasB1 = {bB1, bB1, bB1, bB1};
    const int arow = (nq & 7) * RS + quad * 8;   // A row m = h[batch m&7]
    const int xoff = (quad & 1) * 4;             // this quad's 4-batch x group

    // loop-invariant cell-write addressing: this lane's 2 cells are batches
    // b0, b0+1 of its layer; address = b*RS + ucell
    const int e0 = evn ? 0 : 2;                  // kept D-reg base
    const int b0 = (quad * 4 + e0) & 7;
    const int waddr = b0 * RS + ucell;
    _Float16* const hdw[2] = { l0q ? h0_lds[1] : h1_lds[1],    // writes when pp=0
                               l0q ? h0_lds[0] : h1_lds[0] };  // writes when pp=1

    f32x2 cst2 = {0.f, 0.f};      // c-state for this lane's 2 cells
    float hl0 = 0.f, hl1 = 0.f;   // last h (L1 lanes keep H1[512])

    __syncthreads();

    // seeds for k=0 (carried; next step's seeds computed in MFMA shadow)
    f32x4 cA, cB;
    {
        const float4 xv = *(const float4*)&x_lds[0 * MB + xoff];
        cA[0] = fmaf(xv.x, wxA, bA0); cA[1] = fmaf(xv.y, wxA, bA0);
        cA[2] = fmaf(xv.z, wxA, bA0); cA[3] = fmaf(xv.w, wxA, bA0);
        cB[0] = fmaf(xv.x, wxB, bB0); cB[1] = fmaf(xv.y, wxB, bB0);
        cB[2] = fmaf(xv.z, wxB, bB0); cB[3] = fmaf(xv.w, wxB, bB0);
    }

    auto step = [&](int xk_next, int pp, bool maskK0) {
        const f16x8 a00 = *(const f16x8*)&h0_lds[pp][arow];
        const f16x8 a01 = *(const f16x8*)&h0_lds[pp][arow + 32];
        const f16x8 a10 = *(const f16x8*)&h1_lds[pp][arow];
        const f16x8 a11 = *(const f16x8*)&h1_lds[pp][arow + 32];

        // L0: two 2-chains (seeded with bias+x*w); L1: two 4-chains (bias C)
        f32x4 tA = __builtin_amdgcn_mfma_f32_16x16x32_f16(a00, wA0[0], cA, 0, 0, 0);
        f32x4 tB = __builtin_amdgcn_mfma_f32_16x16x32_f16(a00, wB0[0], cB, 0, 0, 0);
        f32x4 uA = __builtin_amdgcn_mfma_f32_16x16x32_f16(a00, wiA[0], biasA1, 0, 0, 0);
        f32x4 uB = __builtin_amdgcn_mfma_f32_16x16x32_f16(a00, wiB[0], biasB1, 0, 0, 0);
        tA = __builtin_amdgcn_mfma_f32_16x16x32_f16(a01, wA0[1], tA, 0, 0, 0);
        tB = __builtin_amdgcn_mfma_f32_16x16x32_f16(a01, wB0[1], tB, 0, 0, 0);
        uA = __builtin_amdgcn_mfma_f32_16x16x32_f16(a01, wiA[1], uA, 0, 0, 0);
        uB = __builtin_amdgcn_mfma_f32_16x16x32_f16(a01, wiB[1], uB, 0, 0, 0);
        uA = __builtin_amdgcn_mfma_f32_16x16x32_f16(a10, whA[0], uA, 0, 0, 0);
        uB = __builtin_amdgcn_mfma_f32_16x16x32_f16(a10, whB[0], uB, 0, 0, 0);
        uA = __builtin_amdgcn_mfma_f32_16x16x32_f16(a11, whA[1], uA, 0, 0, 0);
        uB = __builtin_amdgcn_mfma_f32_16x16x32_f16(a11, whB[1], uB, 0, 0, 0);

        // next-step seeds in the MFMA shadow (independent of MFMA results)
        {
            const float4 xv = *(const float4*)&x_lds[xk_next * MB + xoff];
            cA[0] = fmaf(xv.x, wxA, bA0); cA[1] = fmaf(xv.y, wxA, bA0);
            cA[2] = fmaf(xv.z, wxA, bA0); cA[3] = fmaf(xv.w, wxA, bA0);
            cB[0] = fmaf(xv.x, wxB, bB0); cB[1] = fmaf(xv.y, wxB, bB0);
            cB[2] = fmaf(xv.z, wxB, bB0); cB[3] = fmaf(xv.w, wxB, bB0);
        }

        const bool docell = maskK0 ? l0q : true;   // only k=0 masks L1 quads
        if (docell) {
            float sA[4], sB[4];
            #pragma unroll
            for (int r = 0; r < 4; ++r) {
                const float pA = l0q ? tA[r] : uA[r];    // pre-scaled args
                const float pB = l0q ? tB[r] : uB[r];
                sA[r] = __builtin_amdgcn_rcpf(1.f + __builtin_amdgcn_exp2f(pA));
                sB[r] = fmaf(AB, __builtin_amdgcn_rcpf(1.f + __builtin_amdgcn_exp2f(pB)), BB);
            }
            const float rxA0 = __shfl_xor(evn ? sA[2] : sA[0], 1);
            const float rxA1 = __shfl_xor(evn ? sA[3] : sA[1], 1);
            const float rxB0 = __shfl_xor(evn ? sB[2] : sB[0], 1);
            const float rxB1 = __shfl_xor(evn ? sB[3] : sB[1], 1);
            f32x2 iv2, fv2, gv2, ov2;
            iv2.x = evn ? sA[0] : rxA0;  iv2.y = evn ? sA[1] : rxA1;
            fv2.x = evn ? rxA0 : sA[2];  fv2.y = evn ? rxA1 : sA[3];
            gv2.x = evn ? sB[0] : rxB0;  gv2.y = evn ? sB[1] : rxB1;
            ov2.x = evn ? rxB0 : sB[2];  ov2.y = evn ? rxB1 : sB[3];
            cst2 = fv2 * cst2 + iv2 * gv2;           // v_pk_fma pair
            f32x2 ex, rc;
            ex.x = __builtin_amdgcn_exp2f(KTANH * cst2.x);
            ex.y = __builtin_amdgcn_exp2f(KTANH * cst2.y);
            rc.x = __builtin_amdgcn_rcpf(1.f + ex.x);
            rc.y = __builtin_amdgcn_rcpf(1.f + ex.y);
            const f32x2 th = 1.f - 2.f * rc;         // v_pk_fma
            const f32x2 h2 = ov2 * th;               // v_pk_mul
            hl0 = h2.x; hl1 = h2.y;
            _Float16* hdst = (pp == 0) ? hdw[0] : hdw[1];
            hdst[waddr]      = (_Float16)h2.x;
            hdst[waddr + RS] = (_Float16)h2.y;
        }
        __syncthreads();
    };

    // k=0 peeled mask, then branchless; parity literal via manual x2 unroll
    step(1, 0, true);                       // k=0
    for (int k = 1; k < 511; k += 2) {
        step(k + 1, 1, false);              // k   (odd)
        step(k + 2, 0, false);              // k+1 (even); k+2 <= 511
    }
    step(511, 1, false);                    // k=511 (seed index clamped, dead)
    step(511, 0, false);                    // k=512 tail: L1 makes H1[512]

    // ---- epilogue: features = relu(H1[512] @ fcW^T + fcb) ----
    if (!l0q) {
        h1f32[b0 * HID + ucell]       = hl0;
        h1f32[(b0 + 1) * HID + ucell] = hl1;
    }
    __syncthreads();

    if (tid < MB * 32) {
        const int o  = tid & 31;
        const int rr = tid >> 5;
        float acc = fcb_lds[o];
        #pragma unroll 8
        for (int kk = 0; kk < HID; ++kk)
            acc += h1f32[rr * HID + kk] * fcw_lds[o * HID + kk];
        out[(bbase + rr) * 32 + o] = fmaxf(acc, 0.f);
    }
}

extern "C" void kernel_launch(void* const* d_in, const int* in_sizes, int n_in,
                              void* d_out, int out_size, void* d_ws, size_t ws_size,
                              hipStream_t stream) {
    const float* x    = (const float*)d_in[0];
    const float* Wih0 = (const float*)d_in[1];
    const float* Whh0 = (const float*)d_in[2];
    const float* bih0 = (const float*)d_in[3];
    const float* bhh0 = (const float*)d_in[4];
    const float* Wih1 = (const float*)d_in[5];
    const float* Whh1 = (const float*)d_in[6];
    const float* bih1 = (const float*)d_in[7];
    const float* bhh1 = (const float*)d_in[8];
    const float* fcW  = (const float*)d_in[9];
    const float* fcb  = (const float*)d_in[10];
    float* out = (float*)d_out;

    lstm_feat_kernel<<<2048 / MB, 512, 0, stream>>>(
        x, Wih0, Whh0, bih0, bhh0, Wih1, Whh1, bih1, bhh1, fcW, fcb, out);
}